// Round 4
// baseline (215.793 us; speedup 1.0000x reference)
//
#include <hip/hip_runtime.h>

// SparseAttention: B=8, M=N=4096, K=64, R=128 nnz/row (uniform CSR, cols sorted per row).
// R3 was L2 random-gather line-rate bound (~14 lines/cy/XCD of ~16): every edge paid
// 2x128B gathers. R4: flash-style column-tiled kernel — stage K/V tiles (fp16) into LDS
// via sequential streams, walk each row's sorted cols with a running pointer, online
// softmax in registers. Gather traffic 1.07 GB -> 268 MB sequential; new floor = LDS pipe.
#define Bc 8
#define Mc 4096
#define Nc 4096
#define Kc 64
#define Rc 128
#define TILE 256              // columns per LDS tile
#define NT (Nc / TILE)        // 16 tiles
#define RPB 128               // rows per block
#define THREADS 1024
#define KSTRIDE 72            // h16 units per LDS row: 64 + 8 pad (144 B, keeps 16B align)

typedef _Float16 h16;
typedef h16 h16x2 __attribute__((ext_vector_type(2)));
typedef h16 h16x4 __attribute__((ext_vector_type(4)));
typedef h16 h16x8 __attribute__((ext_vector_type(8)));

// fp32 -> fp16 staging for K and V (read 16.8 MB, write 8.4 MB).
__global__ __launch_bounds__(256) void cvt_fp16(
    const float4* __restrict__ K4, const float4* __restrict__ V4,
    h16x4* __restrict__ Kh4, h16x4* __restrict__ Vh4)
{
    const int n4 = Bc * Nc * Kc / 4;
    int i = blockIdx.x * 256 + threadIdx.x;
    const float4* src; h16x4* dst; int idx;
    if (i < n4) { src = K4; dst = Kh4; idx = i; }
    else        { src = V4; dst = Vh4; idx = i - n4; }
    float4 v = src[idx];
    h16x4 o = { (h16)v.x, (h16)v.y, (h16)v.z, (h16)v.w };
    dst[idx] = o;
}

__global__ __launch_bounds__(THREADS, 4) void sattn_kernel(
    const int* __restrict__ cols,    // [M,R], cols sorted within each row (batch-shared)
    const float* __restrict__ Q,     // [B,M,K] fp32
    const h16* __restrict__ Kh,      // [B,N,K] fp16 (staged)
    const h16* __restrict__ Vh,      // [B,N,K] fp16 (staged)
    float* __restrict__ out)         // [B,M,K] fp32
{
    const int b     = blockIdx.x & 7;    // XCD swizzle: one batch per XCD's L2
    const int chunk = blockIdx.x >> 3;   // 0..31 (128-row chunk)
    const int t     = threadIdx.x;
    const int g     = t >> 3;            // row-group 0..127
    const int ln    = t & 7;             // lane-in-group (k-slice owner: k = ln*8..ln*8+7)
    const int laneid = t & 63;
    const int gbase  = laneid & 56;      // first lane of this group within the wave

    __shared__ __align__(16) h16 s_k[TILE * KSTRIDE];  // 36 KB
    __shared__ __align__(16) h16 s_v[TILE * KSTRIDE];  // 36 KB

    const int row = chunk * RPB + g;
    const int* colbase = cols + row * Rc;

    // Q fragment (fp32 -> fp16x2 pairs for fdot2), held in registers for the whole kernel.
    const float* qp = Q + (((size_t)b * Mc + row) << 6) + ln * 8;
    float4 q0 = *(const float4*)qp, q1 = *(const float4*)(qp + 4);
    h16x2 qh[4];
    qh[0] = h16x2{ (h16)q0.x, (h16)q0.y };
    qh[1] = h16x2{ (h16)q0.z, (h16)q0.w };
    qh[2] = h16x2{ (h16)q1.x, (h16)q1.y };
    qh[3] = h16x2{ (h16)q1.z, (h16)q1.w };

    // Online-softmax state (replicated identically across the 8 lanes of a group).
    float mrun = -1e30f, lrun = 0.f;
    float acc8[8] = {0.f,0.f,0.f,0.f,0.f,0.f,0.f,0.f};
    int p = 0;                            // running edge pointer into this row's sorted cols

    for (int tile = 0; tile < NT; ++tile) {
        const int c0   = tile * TILE;
        const int cend = c0 + TILE;

        __syncthreads();   // previous tile's readers done before overwrite
        // Stage K/V tile: 2x32KB sequential from L2, lane-contiguous 16B chunks.
        #pragma unroll
        for (int i = 0; i < 2; ++i) {
            const int c  = t + i * 1024;        // 16B-chunk id, 0..2047
            const int r  = c >> 3;
            const int l8 = c & 7;
            const size_t goff = ((((size_t)b * Nc) + c0 + r) << 6) + l8 * 8;
            *(h16x8*)&s_k[r * KSTRIDE + l8 * 8] = *(const h16x8*)(Kh + goff);
            *(h16x8*)&s_v[r * KSTRIDE + l8 * 8] = *(const h16x8*)(Vh + goff);
        }
        __syncthreads();

        // Walk this row's edges that fall in [c0, cend), in chunks of <= 8.
        for (;;) {
            const int myp   = p + ln;
            const int mycol = (myp < Rc) ? colbase[myp] : 0x7fffffff;
            const bool valid = mycol < cend;      // sorted -> valid lanes form a prefix
            unsigned long long bal = __ballot(valid);
            const int cnt = __popcll((bal >> gbase) & 0xFFull);
            if (cnt == 0) break;

            // Pass 1: logits for the chunk (jointly, 8 lanes per edge), chunk max.
            float mylogit = 0.f;
            float mchunk  = -1e30f;
            for (int j = 0; j < cnt; ++j) {
                const int colj = __shfl(mycol, gbase | j, 64);
                const h16x8 kv = *(const h16x8*)&s_k[(colj - c0) * KSTRIDE + ln * 8];
                float d = 0.f;
                d = __builtin_amdgcn_fdot2(qh[0], h16x2{kv[0], kv[1]}, d, false);
                d = __builtin_amdgcn_fdot2(qh[1], h16x2{kv[2], kv[3]}, d, false);
                d = __builtin_amdgcn_fdot2(qh[2], h16x2{kv[4], kv[5]}, d, false);
                d = __builtin_amdgcn_fdot2(qh[3], h16x2{kv[6], kv[7]}, d, false);
                d += __shfl_xor(d, 1, 64);
                d += __shfl_xor(d, 2, 64);
                d += __shfl_xor(d, 4, 64);   // all 8 lanes now hold the logit
                if (ln == j) mylogit = d;
                mchunk = fmaxf(mchunk, d);
            }

            // Online-softmax rescale (all group lanes compute identically).
            const float mnew  = fmaxf(mrun, mchunk);
            const float alpha = __expf(mrun - mnew);
            lrun *= alpha;
            #pragma unroll
            for (int k = 0; k < 8; ++k) acc8[k] *= alpha;
            mrun = mnew;

            // Pass 2: weights + PV accumulate from the V tile.
            for (int j = 0; j < cnt; ++j) {
                const int src  = gbase | j;
                const float lg = __shfl(mylogit, src, 64);
                const int colj = __shfl(mycol, src, 64);
                const float w  = __expf(lg - mrun);
                lrun += w;
                const h16x8 vv = *(const h16x8*)&s_v[(colj - c0) * KSTRIDE + ln * 8];
                #pragma unroll
                for (int k = 0; k < 8; ++k)
                    acc8[k] = fmaf((float)vv[k], w, acc8[k]);
            }

            p += cnt;
            if (cnt < 8) break;   // tile exhausted for this row
        }
    }

    // Epilogue: normalize and store (wave writes 8 consecutive rows, fully coalesced).
    const float inv = 1.0f / lrun;
    float4 o0 = { acc8[0]*inv, acc8[1]*inv, acc8[2]*inv, acc8[3]*inv };
    float4 o1 = { acc8[4]*inv, acc8[5]*inv, acc8[6]*inv, acc8[7]*inv };
    float* op = out + (((size_t)b * Mc + row) << 6) + ln * 8;
    *(float4*)op       = o0;
    *(float4*)(op + 4) = o1;
}

extern "C" void kernel_launch(void* const* d_in, const int* in_sizes, int n_in,
                              void* d_out, int out_size, void* d_ws, size_t ws_size,
                              hipStream_t stream) {
    // inputs: 0 row_indices, 1 row_offsets, 2 column_indices, 3 q3d, 4 k3d, 5 v3d, 6 values
    const int*   cols = (const int*)d_in[2];
    const float* Q    = (const float*)d_in[3];
    const float* Km   = (const float*)d_in[4];
    const float* Vm   = (const float*)d_in[5];
    float* out = (float*)d_out;

    h16* Kh = (h16*)d_ws;
    h16* Vh = Kh + (size_t)Bc * Nc * Kc;   // 4.19 MB each in d_ws

    const int n4 = Bc * Nc * Kc / 4;
    cvt_fp16<<<dim3(2 * n4 / 256), dim3(256), 0, stream>>>(
        (const float4*)Km, (const float4*)Vm, (h16x4*)Kh, (h16x4*)Vh);
    sattn_kernel<<<dim3(Bc * (Mc / RPB)), dim3(THREADS), 0, stream>>>(cols, Q, Kh, Vh, out);
}

// Round 5
// 157.948 us; speedup vs baseline: 1.3662x; 1.3662x over previous
//
#include <hip/hip_runtime.h>

// SparseAttention: B=8, M=N=4096, K=64, R=128 nnz/row (uniform CSR).
// R3 (proven, 62us): fp16-staged K/V, 8-lane-per-edge coalesced gathers. Both R2(fp32)
// and R3(fp16) hit the same ~17.5 TB/s gather ceiling (=half of L2 streaming ubench),
// at ~99% L2 hit -> hypothesis: L1 fill/alloc on discontiguous gathered lines is the wall.
// R5: identical to R3 but K/V gathers are __builtin_nontemporal_load (bypass L1 alloc).
#define Bc 8
#define Mc 4096
#define Nc 4096
#define Kc 64
#define Rc 128

typedef _Float16 h16;
typedef h16 h16x2 __attribute__((ext_vector_type(2)));
typedef h16 h16x4 __attribute__((ext_vector_type(4)));
typedef h16 h16x8 __attribute__((ext_vector_type(8)));

// fp32 -> fp16 staging for K and V (read 16.8 MB, write 8.4 MB).
__global__ __launch_bounds__(256) void cvt_fp16(
    const float4* __restrict__ K4, const float4* __restrict__ V4,
    h16x4* __restrict__ Kh4, h16x4* __restrict__ Vh4)
{
    const int n4 = Bc * Nc * Kc / 4;  // 524288 float4-groups per tensor
    int i = blockIdx.x * 256 + threadIdx.x;
    const float4* src; h16x4* dst; int idx;
    if (i < n4) { src = K4; dst = Kh4; idx = i; }
    else        { src = V4; dst = Vh4; idx = i - n4; }
    float4 v = src[idx];
    h16x4 o = { (h16)v.x, (h16)v.y, (h16)v.z, (h16)v.w };
    dst[idx] = o;
}

__global__ __launch_bounds__(256) void sattn_kernel(
    const int* __restrict__ cols,    // [M*R], sorted within row
    const float* __restrict__ Q,     // [B,M,K] fp32
    const h16* __restrict__ Kh,      // [B,N,K] fp16 (staged)
    const h16* __restrict__ Vh,      // [B,N,K] fp16 (staged)
    float* __restrict__ out)         // [B,M,K] fp32
{
    const int b   = blockIdx.x & 7;   // XCD swizzle: one batch per XCD's L2 (K+V fp16 = 2 MiB < 4 MiB)
    const int row = blockIdx.x >> 3;
    const int t   = threadIdx.x;
    const int g   = t >> 3;           // group 0..31 (8 lanes per edge)
    const int ln  = t & 7;            // lane-in-group; handles k = ln*8 .. ln*8+7

    __shared__ float s_w[Rc];                      // logits -> exp(l-m)
    __shared__ __align__(16) float s_part[32][Kc]; // 8 KB partials
    __shared__ __align__(16) float s_red[4][Kc];   // 1 KB stage-2
    __shared__ float s_invden;

    // Per-thread columns for its 4 edges (8 lanes/group read same addr -> L1 broadcast).
    int col4[4];
    #pragma unroll
    for (int p = 0; p < 4; ++p) col4[p] = cols[row * Rc + p * 32 + g];

    // Q fragment: 8 floats at k = ln*8 (whole wave reads same 256B row -> L1-hot), cvt to fp16.
    const float4* qp = (const float4*)(Q + (((unsigned)b * Mc + row) << 6) + ln * 8);
    float4 q0 = qp[0], q1 = qp[1];
    h16x2 qh[4];
    qh[0] = h16x2{ (h16)q0.x, (h16)q0.y };
    qh[1] = h16x2{ (h16)q0.z, (h16)q0.w };
    qh[2] = h16x2{ (h16)q1.x, (h16)q1.y };
    qh[3] = h16x2{ (h16)q1.z, (h16)q1.w };

    // ---- SDDMM: preload all 4 K fragments; nt -> bypass L1 allocation (no intra-CU reuse). ----
    h16x8 kv[4];
    #pragma unroll
    for (int p = 0; p < 4; ++p)
        kv[p] = __builtin_nontemporal_load(
            (const h16x8*)(Kh + ((((unsigned)b * Nc + col4[p]) << 6) + ln * 8)));

    #pragma unroll
    for (int p = 0; p < 4; ++p) {
        float acc = 0.f;
        #pragma unroll
        for (int j = 0; j < 4; ++j) {
            h16x2 kj = { kv[p][2 * j], kv[p][2 * j + 1] };
            acc = __builtin_amdgcn_fdot2(qh[j], kj, acc, false);
        }
        // Reduce across the 8 lanes of the group.
        acc += __shfl_xor(acc, 1, 64);
        acc += __shfl_xor(acc, 2, 64);
        acc += __shfl_xor(acc, 4, 64);
        if (ln == 0) s_w[p * 32 + g] = acc;
    }

    // ---- V prefetch (nt): independent of softmax; overlaps the barrier's vmcnt drain. ----
    h16x8 vv[4];
    #pragma unroll
    for (int p = 0; p < 4; ++p)
        vv[p] = __builtin_nontemporal_load(
            (const h16x8*)(Vh + ((((unsigned)b * Nc + col4[p]) << 6) + ln * 8)));

    __syncthreads();

    // ---- Softmax over the 128 logits (wave 0) ----
    if (t < 64) {
        float l0 = s_w[t], l1 = s_w[t + 64];
        float m = fmaxf(l0, l1);
        #pragma unroll
        for (int o = 32; o; o >>= 1) m = fmaxf(m, __shfl_xor(m, o, 64));
        float e0 = __expf(l0 - m), e1 = __expf(l1 - m);
        s_w[t] = e0; s_w[t + 64] = e1;
        float s = e0 + e1;
        #pragma unroll
        for (int o = 32; o; o >>= 1) s += __shfl_xor(s, o, 64);
        if (t == 0) s_invden = 1.0f / s;
    }
    __syncthreads();

    // ---- SPMM: acc8[k] += w_e * V[col_e, k] over this group's 4 edges ----
    float acc8[8] = {0.f,0.f,0.f,0.f,0.f,0.f,0.f,0.f};
    #pragma unroll
    for (int p = 0; p < 4; ++p) {
        const float w = s_w[p * 32 + g];
        #pragma unroll
        for (int j = 0; j < 8; ++j)
            acc8[j] = fmaf((float)vv[p][j], w, acc8[j]);
    }
    *(float4*)&s_part[g][ln * 8]     = *(float4*)&acc8[0];
    *(float4*)&s_part[g][ln * 8 + 4] = *(float4*)&acc8[4];
    __syncthreads();

    // ---- Two-stage cross-group reduction (all 256 threads) ----
    {
        const int k = t & 63, qq = t >> 6;
        float r = 0.f;
        #pragma unroll
        for (int j = 0; j < 8; ++j) r += s_part[qq * 8 + j][k];
        s_red[qq][k] = r;
    }
    __syncthreads();
    if (t < 64) {
        float r = (s_red[0][t] + s_red[1][t]) + (s_red[2][t] + s_red[3][t]);
        out[(((unsigned)b * Mc + row) << 6) + t] = r * s_invden;
    }
}

extern "C" void kernel_launch(void* const* d_in, const int* in_sizes, int n_in,
                              void* d_out, int out_size, void* d_ws, size_t ws_size,
                              hipStream_t stream) {
    // inputs: 0 row_indices, 1 row_offsets, 2 column_indices, 3 q3d, 4 k3d, 5 v3d, 6 values
    const int*   cols = (const int*)d_in[2];
    const float* Q    = (const float*)d_in[3];
    const float* Km   = (const float*)d_in[4];
    const float* Vm   = (const float*)d_in[5];
    float* out = (float*)d_out;

    h16* Kh = (h16*)d_ws;
    h16* Vh = Kh + (size_t)Bc * Nc * Kc;   // 4.19 MB each in d_ws

    const int n4 = Bc * Nc * Kc / 4;
    cvt_fp16<<<dim3(2 * n4 / 256), dim3(256), 0, stream>>>(
        (const float4*)Km, (const float4*)Vm, (h16x4*)Kh, (h16x4*)Vh);
    sattn_kernel<<<dim3(Bc * Mc), dim3(256), 0, stream>>>(cols, Q, Kh, Vh, out);
}

// Round 6
// 147.451 us; speedup vs baseline: 1.4635x; 1.0712x over previous
//
#include <hip/hip_runtime.h>

// SparseAttention: B=8, M=N=4096, K=64, R=128 nnz/row (uniform CSR).
// R3 (62us) sits at ~88% of the pure-L2 aggregate BW ceiling (~19.6 TB/s = 16ch x 64B
// x 2.4GHz x 8 XCD) while HBM is 91% idle. R5 proved nt loads are NOT retained in L2.
// R6: column-hash traffic split — cols with (c&7)==7 (12.5%) are always nt-loaded ->
// never L2-resident -> served by HBM in parallel with L2 serving the other 87.5%.
#define Bc 8
#define Mc 4096
#define Nc 4096
#define Kc 64
#define Rc 128

typedef _Float16 h16;
typedef h16 h16x2 __attribute__((ext_vector_type(2)));
typedef h16 h16x4 __attribute__((ext_vector_type(4)));
typedef h16 h16x8 __attribute__((ext_vector_type(8)));

// fp32 -> fp16 staging for K and V (read 16.8 MB, write 8.4 MB).
__global__ __launch_bounds__(256) void cvt_fp16(
    const float4* __restrict__ K4, const float4* __restrict__ V4,
    h16x4* __restrict__ Kh4, h16x4* __restrict__ Vh4)
{
    const int n4 = Bc * Nc * Kc / 4;  // 524288 float4-groups per tensor
    int i = blockIdx.x * 256 + threadIdx.x;
    const float4* src; h16x4* dst; int idx;
    if (i < n4) { src = K4; dst = Kh4; idx = i; }
    else        { src = V4; dst = Vh4; idx = i - n4; }
    float4 v = src[idx];
    h16x4 o = { (h16)v.x, (h16)v.y, (h16)v.z, (h16)v.w };
    dst[idx] = o;
}

__global__ __launch_bounds__(256) void sattn_kernel(
    const int* __restrict__ cols,    // [M*R], sorted within row
    const float* __restrict__ Q,     // [B,M,K] fp32
    const h16* __restrict__ Kh,      // [B,N,K] fp16 (staged)
    const h16* __restrict__ Vh,      // [B,N,K] fp16 (staged)
    float* __restrict__ out)         // [B,M,K] fp32
{
    const int b   = blockIdx.x & 7;   // XCD swizzle: one batch's K/V resident in one XCD's L2
    const int row = blockIdx.x >> 3;
    const int t   = threadIdx.x;
    const int g   = t >> 3;           // group 0..31 (8 lanes per edge)
    const int ln  = t & 7;            // lane-in-group; handles k = ln*8 .. ln*8+7

    __shared__ float s_w[Rc];                      // logits -> exp(l-m)
    __shared__ __align__(16) float s_part[32][Kc]; // 8 KB partials
    __shared__ __align__(16) float s_red[4][Kc];   // 1 KB stage-2
    __shared__ float s_invden;

    // Per-thread columns for its 4 edges (8 lanes/group read same addr -> broadcast).
    int col4[4];
    #pragma unroll
    for (int p = 0; p < 4; ++p) col4[p] = cols[row * Rc + p * 32 + g];

    // Q fragment: 8 floats at k = ln*8, cvt to fp16 pairs for fdot2.
    const float4* qp = (const float4*)(Q + (((unsigned)b * Mc + row) << 6) + ln * 8);
    float4 q0 = qp[0], q1 = qp[1];
    h16x2 qh[4];
    qh[0] = h16x2{ (h16)q0.x, (h16)q0.y };
    qh[1] = h16x2{ (h16)q0.z, (h16)q0.w };
    qh[2] = h16x2{ (h16)q1.x, (h16)q1.y };
    qh[3] = h16x2{ (h16)q1.z, (h16)q1.w };

    // ---- SDDMM: preload 4 K fragments. Column-hash split: (col&7)==7 -> nt (HBM lane),
    //      else normal (L2 lane). Must be column-keyed so nt cols are NEVER L2-refilled. ----
    h16x8 kv[4];
    #pragma unroll
    for (int p = 0; p < 4; ++p) {
        const h16x8* ap = (const h16x8*)(Kh + ((((unsigned)b * Nc + col4[p]) << 6) + ln * 8));
        if ((col4[p] & 7) == 7) kv[p] = __builtin_nontemporal_load(ap);
        else                    kv[p] = *ap;
    }

    #pragma unroll
    for (int p = 0; p < 4; ++p) {
        float acc = 0.f;
        #pragma unroll
        for (int j = 0; j < 4; ++j) {
            h16x2 kj = { kv[p][2 * j], kv[p][2 * j + 1] };
            acc = __builtin_amdgcn_fdot2(qh[j], kj, acc, false);
        }
        acc += __shfl_xor(acc, 1, 64);
        acc += __shfl_xor(acc, 2, 64);
        acc += __shfl_xor(acc, 4, 64);
        if (ln == 0) s_w[p * 32 + g] = acc;
    }

    // ---- V prefetch (same column-hash split); overlaps the barrier's vmcnt drain. ----
    h16x8 vv[4];
    #pragma unroll
    for (int p = 0; p < 4; ++p) {
        const h16x8* ap = (const h16x8*)(Vh + ((((unsigned)b * Nc + col4[p]) << 6) + ln * 8));
        if ((col4[p] & 7) == 7) vv[p] = __builtin_nontemporal_load(ap);
        else                    vv[p] = *ap;
    }

    __syncthreads();

    // ---- Softmax over the 128 logits (wave 0) ----
    if (t < 64) {
        float l0 = s_w[t], l1 = s_w[t + 64];
        float m = fmaxf(l0, l1);
        #pragma unroll
        for (int o = 32; o; o >>= 1) m = fmaxf(m, __shfl_xor(m, o, 64));
        float e0 = __expf(l0 - m), e1 = __expf(l1 - m);
        s_w[t] = e0; s_w[t + 64] = e1;
        float s = e0 + e1;
        #pragma unroll
        for (int o = 32; o; o >>= 1) s += __shfl_xor(s, o, 64);
        if (t == 0) s_invden = 1.0f / s;
    }
    __syncthreads();

    // ---- SPMM: acc8[k] += w_e * V[col_e, k] over this group's 4 edges ----
    float acc8[8] = {0.f,0.f,0.f,0.f,0.f,0.f,0.f,0.f};
    #pragma unroll
    for (int p = 0; p < 4; ++p) {
        const float w = s_w[p * 32 + g];
        #pragma unroll
        for (int j = 0; j < 8; ++j)
            acc8[j] = fmaf((float)vv[p][j], w, acc8[j]);
    }
    *(float4*)&s_part[g][ln * 8]     = *(float4*)&acc8[0];
    *(float4*)&s_part[g][ln * 8 + 4] = *(float4*)&acc8[4];
    __syncthreads();

    // ---- Two-stage cross-group reduction (all 256 threads) ----
    {
        const int k = t & 63, qq = t >> 6;
        float r = 0.f;
        #pragma unroll
        for (int j = 0; j < 8; ++j) r += s_part[qq * 8 + j][k];
        s_red[qq][k] = r;
    }
    __syncthreads();
    if (t < 64) {
        float r = (s_red[0][t] + s_red[1][t]) + (s_red[2][t] + s_red[3][t]);
        out[(((unsigned)b * Mc + row) << 6) + t] = r * s_invden;
    }
}

extern "C" void kernel_launch(void* const* d_in, const int* in_sizes, int n_in,
                              void* d_out, int out_size, void* d_ws, size_t ws_size,
                              hipStream_t stream) {
    // inputs: 0 row_indices, 1 row_offsets, 2 column_indices, 3 q3d, 4 k3d, 5 v3d, 6 values
    const int*   cols = (const int*)d_in[2];
    const float* Q    = (const float*)d_in[3];
    const float* Km   = (const float*)d_in[4];
    const float* Vm   = (const float*)d_in[5];
    float* out = (float*)d_out;

    h16* Kh = (h16*)d_ws;
    h16* Vh = Kh + (size_t)Bc * Nc * Kc;   // 4.19 MB each in d_ws

    const int n4 = Bc * Nc * Kc / 4;
    cvt_fp16<<<dim3(2 * n4 / 256), dim3(256), 0, stream>>>(
        (const float4*)Km, (const float4*)Vm, (h16x4*)Kh, (h16x4*)Vh);
    sattn_kernel<<<dim3(Bc * Mc), dim3(256), 0, stream>>>(cols, Q, Kh, Vh, out);
}